// Round 7
// baseline (352.378 us; speedup 1.0000x reference)
//
#include <hip/hip_runtime.h>
#include <math.h>

// SGRUCell T=32 B=8 I=512 H=512, all f32.
// Persistent kernel: block (q=blk>>3, b=blk&7) owns rows i in [16q,16q+16) of
// batch b; 16 waves, one row per wave. All per-row tables in registers
// (~72 persistent VGPRs); amdgpu_waves_per_eu(4,4) caps occupancy at the one
// resident block we need and unlocks the 128-VGPR budget (round-6 spilled at
// VGPR=64: WRITE_SIZE 24.9 MB vs 17.4 ideal). x-projection precomputed for
// all 32 steps into LDS. Cross-block sync is data-as-flag: producers store
// h+1.0 (>=1.0) into ws exchange slots with relaxed agent atomics; consumers
// poll their own slot until >=0.5 (0xAA poison decodes <0.5). One LLC
// round-trip per step, no fences, no flags, no producer-side drain.

__device__ __forceinline__ float wred(float v) {
#pragma unroll
  for (int o = 32; o > 0; o >>= 1) v += __shfl_xor(v, o, 64);
  return v;
}
__device__ __forceinline__ float sigm(float x) { return 1.f / (1.f + __expf(-x)); }

__global__ void prenorm_kernel(const float* __restrict__ xv, const float* __restrict__ xg,
                               const float* __restrict__ hv, const float* __restrict__ hg,
                               float* __restrict__ scx, float* __restrict__ sch) {
  int r = blockIdx.x, L = threadIdx.x;
  const float* vrow; const float* g; float* o; int rr;
  if (r < 1536) { rr = r; vrow = xv + (size_t)r * 512; g = xg; o = scx; }
  else { rr = r - 1536; vrow = hv + (size_t)rr * 512; g = hg; o = sch; }
  float s = 0.f;
#pragma unroll
  for (int m = 0; m < 8; m++) { float v = vrow[m * 64 + L]; s = fmaf(v, v, s); }
  s = wred(s);
  if (L == 0) o[rr] = g[rr] / sqrtf(s);
}

__global__ __launch_bounds__(1024)
__attribute__((amdgpu_waves_per_eu(4, 4))) void persist_kernel(
    const float* __restrict__ x,
    const float* __restrict__ h0, const float* __restrict__ v0,
    const float* __restrict__ dU0, const float* __restrict__ te0,
    const float* __restrict__ tE0,
    const float* __restrict__ x2h_v, const float* __restrict__ x2h_b,
    const float* __restrict__ h2h_v, const float* __restrict__ h2h_b,
    const float* __restrict__ alpha,
    const float* __restrict__ h2mod_w, const float* __restrict__ h2mod_b,
    const float* __restrict__ modU_w, const float* __restrict__ modU_b,
    const float* __restrict__ scx, const float* __restrict__ sch,
    unsigned* __restrict__ hx,
    float* __restrict__ o_v, float* __restrict__ o_h,
    float* __restrict__ o_dU, float* __restrict__ o_te,
    float* __restrict__ o_tE, float* __restrict__ o_outs) {
  __shared__ float sh_hbuf[2][512];   // h ping-pong: buf[t&1] = h_t
  __shared__ float sh_te[512];        // eligibility trace
  __shared__ float sh_mod[2048];      // h2mod_w (4x512)
  __shared__ float sh_xpz[32][16];    // precomputed x-proj (z) + bias, [t][w]
  __shared__ float sh_xpdv[32][16];   // precomputed x-proj (dv) + bias
  __shared__ float sh_gates[4];       // tau_e, tau_E, tau_U, mU

  const int tid = threadIdx.x;
  const int w = tid >> 6, L = tid & 63;
  const int b = blockIdx.x & 7, q = blockIdx.x >> 3;
  const int i = q * 16 + w;  // owned row

  // ---- basic LDS staging ----
  if (tid < 512) {
    sh_hbuf[0][tid] = h0[b * 512 + tid];
    sh_te[tid] = te0[b * 512 + tid];
  }
  sh_mod[tid] = h2mod_w[tid];
  sh_mod[tid + 1024] = h2mod_w[tid + 1024];

  const int rz = i, rdv = 1024 + i, rr = 512 + i;
  const size_t row  = ((size_t)(b * 512 + i)) * 512;
  const size_t wrow = (size_t)i * 512;

  // ---- x-projection precompute (h-independent) ----
  {
    float xz[8], xdv[8];
    const float sx_z = scx[rz], sx_dv = scx[rdv];
#pragma unroll
    for (int m = 0; m < 8; m++) {
      int c = m * 64 + L;
      xz[m]  = sx_z  * x2h_v[(size_t)rz  * 512 + c];
      xdv[m] = sx_dv * x2h_v[(size_t)rdv * 512 + c];
    }
    float bz = 0.f, bdv = 0.f;
    if (L == 0) {
      bz  = x2h_b[i] + h2h_b[i];
      bdv = x2h_b[1024 + i] + h2h_b[1024 + i];
    }
#pragma unroll 4
    for (int t = 0; t < 32; t++) {
      const float* xr = x + (size_t)t * 4096 + b * 512;
      float a = 0.f, d = 0.f;
#pragma unroll
      for (int m = 0; m < 8; m++) {
        int c = m * 64 + L;
        float xv_ = xr[c];
        a = fmaf(xz[m], xv_, a);
        d = fmaf(xdv[m], xv_, d);
      }
      a = wred(a); d = wred(d);
      if (L == 0) { sh_xpz[t][w] = a + bz; sh_xpdv[t][w] = d + bdv; }
    }
  }

  // ---- persistent register tables ----
  float wz[8], wdv[8], mw[8], mb[8], al[8], upS[8], loS[8], D[8], tE[8];
  {
    const float s_z = sch[rz], s_dv = sch[rdv], s_r = sch[rr];
#pragma unroll
    for (int m = 0; m < 8; m++) {
      int c = m * 64 + L;
      wz[m]  = s_z  * h2h_v[(size_t)rz  * 512 + c];
      wdv[m] = s_dv * h2h_v[(size_t)rdv * 512 + c];
      mw[m] = modU_w[wrow + c];
      mb[m] = modU_b[wrow + c];
      float alv = alpha[wrow + c];
      al[m] = alv;
      float wrv = s_r * h2h_v[(size_t)rr * 512 + c];
      float t1 = alv / (alv + 1e-5f);   // alpha-prescaled clip factor
      upS[m] = fmaxf(1.f - wrv, 0.f) * t1;
      loS[m] = -fmaxf(1.f + wrv, 0.f) * t1;
      D[m]  = alv * dU0[row + c];       // scaled state: D = alpha * dU
      tE[m] = tE0[row + c];
    }
  }
  float v_reg = 0.f, hn_last = 0.f, gb = 0.f;
  if (L == 0) {
    v_reg = v0[b * 512 + i];
    if (w < 4) gb = h2mod_b[w];
  }
  __syncthreads();

  for (int t = 0; t <= 32; t++) {
    const int cur = t & 1, prev = cur ^ 1;
    if (t > 0) {
      // ---- stage h_t: poll own slot, data IS the flag (h+1.0 >= 1.0) ----
      if (tid < 512) {
        const unsigned* slot = hx + (size_t)(t - 1) * 4096 + b * 512 + tid;
        unsigned u = __hip_atomic_load(slot, __ATOMIC_RELAXED, __HIP_MEMORY_SCOPE_AGENT);
        while (__uint_as_float(u) < 0.5f) {
          __builtin_amdgcn_s_sleep(1);
          u = __hip_atomic_load(slot, __ATOMIC_RELAXED, __HIP_MEMORY_SCOPE_AGENT);
        }
        sh_hbuf[cur][tid] = __uint_as_float(u) - 1.0f;
      }
      __syncthreads();
      // gates: mod = h_t @ h2mod_w.T + b, waves 0..3
      if (w < 4) {
        float p = 0.f;
        const float* mr = sh_mod + w * 512;
#pragma unroll
        for (int m = 0; m < 8; m++) {
          int c = m * 64 + L;
          p = fmaf(sh_hbuf[cur][c], mr[c], p);
        }
        p = wred(p);
        if (L == 0) {
          p += gb;
          sh_gates[w] = (w == 3) ? fmaxf(p, 0.f) : sigm(p);
        }
      }
      __syncthreads();
      // te_n = te + tau_e*(h_{t-1} - te)
      float taue = sh_gates[0];
      if (tid < 512) sh_te[tid] += taue * (sh_hbuf[prev][tid] - sh_te[tid]);
      __syncthreads();
      // tE / D register update (pure VALU)
      float tauE = sh_gates[1], tauU = sh_gates[2], mU = sh_gates[3];
      float hn_i = sh_hbuf[cur][i], te_i = sh_te[i];
#pragma unroll
      for (int m = 0; m < 8; m++) {
        int j = m * 64 + L;
        float outer = hn_i * sh_te[j] - te_i * sh_hbuf[cur][j];
        float tEn = tE[m] + tauE * (outer - tE[m]);
        float a = fmaf(mU, mw[m], mb[m]);
        float sshr = (a > 0.5f) ? (a - 0.5f) : ((a < -0.5f) ? (a + 0.5f) : 0.f);
        float Dn = D[m] + tauU * (sshr * (al[m] * tEn) - D[m]);
        D[m] = fminf(fmaxf(Dn, loS[m]), upS[m]);
        tE[m] = tEn;
      }
    }

    if (t < 32) {
      // z/dv dots for step t (x-part precomputed; D = alpha*dU)
      float p1 = 0.f, p2 = 0.f;
#pragma unroll
      for (int m = 0; m < 8; m++) {
        int c = m * 64 + L;
        float hc = sh_hbuf[cur][c];
        p1 = fmaf(wz[m], hc, p1);
        p2 = fmaf(wdv[m] + D[m], hc, p2);
      }
      p1 = wred(p1); p2 = wred(p2);
      if (L == 0) {
        float z = sigm(p1 + sh_xpz[t][w]);
        float dv = p2 + sh_xpdv[t][w];
        v_reg += z * (dv - v_reg);
        hn_last = fmaxf(v_reg, 0.f);
        o_outs[(size_t)t * 4096 + b * 512 + i] = hn_last;
        __hip_atomic_store(hx + (size_t)t * 4096 + b * 512 + i,
                           __float_as_uint(hn_last + 1.0f),
                           __ATOMIC_RELAXED, __HIP_MEMORY_SCOPE_AGENT);
      }
      // no drain, no flag: consumers poll the data itself
    }
  }

  // ---- final writes ----
#pragma unroll
  for (int m = 0; m < 8; m++) {
    int c = m * 64 + L;
    float alv = al[m];
    o_dU[row + c] = (alv != 0.f) ? D[m] * __builtin_amdgcn_rcpf(alv) : 0.f;
    o_tE[row + c] = tE[m];
  }
  if (L == 0) {
    o_v[b * 512 + i] = v_reg;
    o_h[b * 512 + i] = hn_last;
  }
  if (q == 0 && tid < 512) o_te[b * 512 + tid] = sh_te[tid];
}

extern "C" void kernel_launch(void* const* d_in, const int* in_sizes, int n_in,
                              void* d_out, int out_size, void* d_ws, size_t ws_size,
                              hipStream_t stream) {
  const float* x       = (const float*)d_in[0];
  const float* h0      = (const float*)d_in[1];
  const float* v0      = (const float*)d_in[2];
  const float* dU0     = (const float*)d_in[3];
  const float* te0     = (const float*)d_in[4];
  const float* tE0     = (const float*)d_in[5];
  const float* x2h_v   = (const float*)d_in[6];
  const float* x2h_g   = (const float*)d_in[7];
  const float* x2h_b   = (const float*)d_in[8];
  const float* h2h_v   = (const float*)d_in[9];
  const float* h2h_g   = (const float*)d_in[10];
  const float* h2h_b   = (const float*)d_in[11];
  const float* alpha   = (const float*)d_in[12];
  const float* h2mod_w = (const float*)d_in[13];
  const float* h2mod_b = (const float*)d_in[14];
  const float* modU_w  = (const float*)d_in[15];
  const float* modU_b  = (const float*)d_in[16];

  float* out = (float*)d_out;
  // output layout: v(4096) h(4096) dU(2097152) te(4096) tE(2097152) outs(131072)
  float* o_v    = out;
  float* o_h    = out + 4096;
  float* o_dU   = out + 8192;
  float* o_te   = out + 2105344;
  float* o_tE   = out + 2109440;
  float* o_outs = out + 4206592;

  unsigned* hx = (unsigned*)d_ws;            // 32*4096 h-exchange slots (512 KB);
                                             // 0xAA poison decodes < 0.5 => "empty"
  float* wsf = (float*)d_ws;
  float* scx = wsf + 131072;                 // 1536
  float* sch = wsf + 132608;                 // 1536

  prenorm_kernel<<<dim3(3072), dim3(64), 0, stream>>>(x2h_v, x2h_g, h2h_v, h2h_g,
                                                      scx, sch);

  persist_kernel<<<dim3(256), dim3(1024), 0, stream>>>(
      x, h0, v0, dU0, te0, tE0, x2h_v, x2h_b, h2h_v, h2h_b, alpha,
      h2mod_w, h2mod_b, modU_w, modU_b, scx, sch, hx,
      o_v, o_h, o_dU, o_te, o_tE, o_outs);
}